// Round 2
// baseline (521.362 us; speedup 1.0000x reference)
//
#include <hip/hip_runtime.h>

// Problem constants (fixed by setup_inputs).
#define N_SAMP 80
#define C_CH   2048
#define HW     256          // 16*16
#define S_TOP  512
#define HW4    64           // HW / 4 (float4 per channel)

// ---------------------------------------------------------------------------
// Kernel A: build sort keys. key = (monotone float bits << 11) | (2047 - ch).
// Greater key  <=>  (score greater) or (score equal and channel lower),
// exactly jax.lax.top_k's descending order with lower-index tie-break.
// Keys are distinct (index in low bits), so sorted position == count of
// strictly-greater keys.
// ---------------------------------------------------------------------------
__global__ __launch_bounds__(256) void build_keys_kernel(
    const float* __restrict__ s_ca, unsigned long long* __restrict__ keys) {
  const unsigned int i = blockIdx.x * 256u + threadIdx.x;  // < 80*2048
  unsigned int b = __float_as_uint(s_ca[i]);
  b ^= (b & 0x80000000u) ? 0xFFFFFFFFu : 0x80000000u;  // monotone transform
  const unsigned int ch = i & (C_CH - 1);
  keys[i] = ((unsigned long long)b << 11) |
            (unsigned long long)(C_CH - 1 - ch);
}

// ---------------------------------------------------------------------------
// Kernel B: rank by counting. rank[n][ch] = #{ch' : key[n][ch'] > key[n][ch]}
// if < S_TOP else -1. One thread per channel; the inner loop reads the row
// with a loop-uniform index -> compiler emits scalar (s_load) streams, the
// compare is 2 VALU per key. No barriers, no LDS.
// ---------------------------------------------------------------------------
__global__ __launch_bounds__(256) void rank_kernel(
    const unsigned long long* __restrict__ keys, int* __restrict__ rank) {
  const unsigned int bx = blockIdx.x;        // 80*8 blocks
  const unsigned int n = bx >> 3;
  const unsigned int ch = ((bx & 7u) << 8) | threadIdx.x;
  const unsigned long long* __restrict__ krow = keys + (size_t)n * C_CH;
  const unsigned long long u = krow[ch];
  int cnt = 0;
#pragma unroll 8
  for (int kk = 0; kk < C_CH; ++kk) cnt += (krow[kk] > u) ? 1 : 0;
  rank[(size_t)n * C_CH + ch] = (cnt < S_TOP) ? cnt : -1;
}

// ---------------------------------------------------------------------------
// Kernel C: merged output. One thread per float4 of x; reads x once, writes
// BOTH the plain and the aug output positions (two coalesced streams).
// All 64 lanes of a wave share (n, ch) -> s/rank/partner/rand_index loads are
// wave-uniform broadcasts; the aug branch is wave-uniform.
// ---------------------------------------------------------------------------
__global__ __launch_bounds__(256) void shuffle_out_kernel(
    const float4* __restrict__ x4, const float* __restrict__ s_ca,
    const int* __restrict__ rand_index, const int* __restrict__ partner,
    const int* __restrict__ rank, float4* __restrict__ out4) {
  const unsigned int p = blockIdx.x * 256u + threadIdx.x;  // float4 idx in x
  const unsigned int n = p >> 17;            // / (2048*64)
  const unsigned int ch = (p >> 6) & (C_CH - 1);
  const unsigned int q = p & 63u;

  const unsigned int g = n >> 4;
  const unsigned int b = n & 15u;

  const float s = s_ca[(size_t)n * C_CH + ch];
  const float4 v = x4[p];

  // plain half: out[g*32 + b]
  const size_t plain_idx = (((size_t)(g * 32u + b) * C_CH + ch) << 6) | q;
  float4 pv;
  pv.x = v.x * s; pv.y = v.y * s; pv.z = v.z * s; pv.w = v.w * s;
  out4[plain_idx] = pv;

  // aug half: out[g*32 + 16 + b]
  float4 av = v;
  const int k = rank[(size_t)n * C_CH + ch];
  if (k >= 0) {
    int jn = (int)n + 1 + partner[n];
    if (jn >= N_SAMP) jn -= N_SAMP;
    const int pc = rand_index[(size_t)n * S_TOP + k];
    const float4 u = x4[(((size_t)jn * C_CH + pc) << 6) | q];
    av.x = 0.7f * v.x + 0.3f * u.x;
    av.y = 0.7f * v.y + 0.3f * u.y;
    av.z = 0.7f * v.z + 0.3f * u.z;
    av.w = 0.7f * v.w + 0.3f * u.w;
  }
  av.x *= s; av.y *= s; av.z *= s; av.w *= s;
  out4[plain_idx + (size_t)16 * C_CH * HW4] = av;
}

extern "C" void kernel_launch(void* const* d_in, const int* in_sizes, int n_in,
                              void* d_out, int out_size, void* d_ws,
                              size_t ws_size, hipStream_t stream) {
  const float* x = (const float*)d_in[0];
  const float* s_ca = (const float*)d_in[1];
  const int* rand_index = (const int*)d_in[2];
  const int* partner = (const int*)d_in[3];
  // d_in[4] = shuffle_num (512, fixed by setup)

  unsigned long long* keys = (unsigned long long*)d_ws;       // 1.31 MB
  int* rank = (int*)((char*)d_ws + (size_t)N_SAMP * C_CH * 8);  // 0.66 MB

  build_keys_kernel<<<(N_SAMP * C_CH) / 256, 256, 0, stream>>>(s_ca, keys);
  rank_kernel<<<N_SAMP * 8, 256, 0, stream>>>(keys, rank);

  // one thread per float4 of x: 80*2048*64 = 10,485,760 -> 40960 blocks
  const int nblocks = (N_SAMP * C_CH * HW4) / 256;
  shuffle_out_kernel<<<nblocks, 256, 0, stream>>>(
      (const float4*)x, s_ca, rand_index, partner, rank, (float4*)d_out);
}